// Round 1
// baseline (256.418 us; speedup 1.0000x reference)
//
#include <hip/hip_runtime.h>
#include <hip/hip_bf16.h>

// Causal attention, B=4 S=2048 E=1024 D=1024, fp32 in/out.
// Round 9: port gemm_qkv to the 256x256 8-phase HipKittens-style schedule
// (guide §5 template): 512 threads = 8 waves (2Mx4N), BK=64, 128 KiB
// double-buffered LDS with st_16x32 XOR swizzle, counted s_waitcnt vmcnt(8)
// checkpoints (never 0 in steady state), raw s_barrier + setprio around the
// 16-MFMA clusters. scores/pv stay on the old 128^2 core this round.

typedef unsigned short u16;
typedef __attribute__((ext_vector_type(4))) u16   u16x4;
typedef __attribute__((ext_vector_type(8))) u16   u16x8;
typedef __attribute__((ext_vector_type(8))) short short8;
typedef __attribute__((ext_vector_type(4))) float f32x4;
typedef __attribute__((ext_vector_type(4))) int   i32x4;

__device__ inline u16 f2b(float v) {
    __hip_bfloat16 b = __float2bfloat16(v);
    return *reinterpret_cast<u16*>(&b);
}
__device__ inline float b2f(u16 v) {
    unsigned int u = ((unsigned int)v) << 16;
    return *reinterpret_cast<float*>(&u);
}

template <typename T> __device__ inline void store_elem(T* p, float v);
template <> __device__ inline void store_elem<float>(float* p, float v) { *p = v; }
template <> __device__ inline void store_elem<u16>(u16* p, float v)     { *p = f2b(v); }

// async global->LDS 16B per lane; LDS dest must be wave-uniform base + lane*16
__device__ inline void gload_lds16(const u16* g, u16* l) {
    __builtin_amdgcn_global_load_lds(
        (const __attribute__((address_space(1))) void*)g,
        (__attribute__((address_space(3))) void*)l, 16, 0, 0);
}

// ---------------- merged fp32 -> bf16 cast: [x | wq | wk | wv] -------------
__global__ __launch_bounds__(256) void cast_all_kernel(
    const float* __restrict__ x,  const float* __restrict__ wq,
    const float* __restrict__ wk, const float* __restrict__ wv,
    u16* __restrict__ dst) {
    int q = blockIdx.x * 256 + threadIdx.x;     // quad index, 2883584 total
    const float* src;
    int sidx;
    if (q < 2097152) { src = x; sidx = q * 4; }
    else {
        int qq = q - 2097152;
        int w  = qq >> 18;                      // 262144 quads per weight
        sidx   = (qq & 262143) * 4;
        src    = (w == 0) ? wq : (w == 1) ? wk : wv;
    }
    float4 v = *(const float4*)(src + sidx);
    u16x4 o;
    o.x = f2b(v.x); o.y = f2b(v.y); o.z = f2b(v.z); o.w = f2b(v.w);
    *(u16x4*)(dst + q * 4) = o;
}

// ---------------- 256x256 8-phase QKV GEMM ---------------------------------
// C = A * B^T, A = xb [8192,1024], B = wb rows [n0..n0+255] (ld 1024).
// bx < 8: dense bf16 store into qk[8192,2048]; bx >= 8: transposed store vt.
__global__ __launch_bounds__(512) void gemm_qkv256(
    const u16* __restrict__ xb, const u16* __restrict__ wb,
    u16* __restrict__ qk, u16* __restrict__ vt)
{
    __shared__ __align__(16) u16 lds[2][2][16384];   // [dbuf][A=0/B=1][256x64]

    const int tid  = threadIdx.x;
    const int lane = tid & 63;
    const int wave = tid >> 6;
    const int quad = lane >> 4;
    const int r16  = lane & 15;
    const int wm   = wave >> 2;   // 0..1  (M direction, 128 rows each)
    const int wn   = wave & 3;    // 0..3  (N direction, 64 cols each)

    int flat = blockIdx.x;                     // 0..383, 384 % 8 == 0
    int swz  = (flat & 7) * 48 + (flat >> 3);  // bijective XCD swizzle
    int bx   = swz % 12;
    int m0   = (swz / 12) * 256;
    const bool isV = (bx >= 8);
    const int  n0  = (isV ? bx - 8 : bx) * 256;
    const u16* __restrict__ Ab = xb;
    const u16* __restrict__ Bb = wb + (isV ? 2048 * 1024 : 0);

    // --- staging precompute: linear LDS dest, inverse-swizzled global src ---
    // LDS tile = 32 subtiles of 16 rows x 32 cols (1024 B); within a subtile
    // rows 8-15 have their 16-col halves XOR-swapped (st_16x32).
    // Stage units: A u=0 -> rowgrps {0-3,8-11}, u=1 -> {4-7,12-15}
    //              B u=0 -> rowgrps {0-7},      u=1 -> {8-15}
    // wave w, load j covers subtile s = j*8+w; lane l -> elems l*8..l*8+7.
    int gA[2][2], gB[2][2], lA[2][2], lB[2][2];
    {
        const int cswz = ((lane & 3) * 8) ^ (((lane >> 5) & 1) << 4);
        const int rsub = lane >> 2;
#pragma unroll
        for (int u = 0; u < 2; ++u)
#pragma unroll
            for (int j = 0; j < 2; ++j) {
                int s   = j * 8 + wave;
                int sh  = s >> 1, cg = s & 1;
                int rgA = (sh & 3) + (sh >> 2) * 8 + u * 4;
                int rgB = sh + u * 8;
                int cl  = cg * 32 + cswz;
                gA[u][j] = (m0 + rgA * 16 + rsub) * 1024 + cl;
                gB[u][j] = (n0 + rgB * 16 + rsub) * 1024 + cl;
                lA[u][j] = (rgA * 2 + cg) * 512 + lane * 8;
                lB[u][j] = (rgB * 2 + cg) * 512 + lane * 8;
            }
    }

#define STAGE_A(BUF, U, KK) do { \
        gload_lds16(Ab + gA[U][0] + (KK), &lds[BUF][0][lA[U][0]]); \
        gload_lds16(Ab + gA[U][1] + (KK), &lds[BUF][0][lA[U][1]]); } while (0)
#define STAGE_B(BUF, U, KK) do { \
        gload_lds16(Bb + gB[U][0] + (KK), &lds[BUF][1][lB[U][0]]); \
        gload_lds16(Bb + gB[U][1] + (KK), &lds[BUF][1][lB[U][1]]); } while (0)

    // --- fragment read bases (same swizzle on the read side) ---
    const int cswr = (quad * 8) ^ ((r16 >> 3) << 4);
    const int rdA0 = wm * 16 * 512 + r16 * 32 + cswr;  // frag (mf,ks): +(mf*2+ks)*512
    const int rdB0 = wn * 8  * 512 + r16 * 32 + cswr;  // frag (nf,ks): +(nf*2+ks)*512

    f32x4 acc[8][4] = {};

    // prologue: tile0 -> buf0, tile1 -> buf1; wait tile0 (8 newest outstanding)
    STAGE_B(0, 0, 0);  STAGE_B(0, 1, 0);  STAGE_A(0, 0, 0);  STAGE_A(0, 1, 0);
    STAGE_B(1, 0, 64); STAGE_B(1, 1, 64); STAGE_A(1, 0, 64); STAGE_A(1, 1, 64);
    asm volatile("s_waitcnt vmcnt(8)" ::: "memory");
    __builtin_amdgcn_s_barrier();

    for (int t = 0; t < 16; ++t) {
        const int  buf = t & 1;
        const int  kk2 = t * 64 + 128;    // K offset of tile t+2 (same buffer)
        const bool pf  = (t < 14);
        const u16* Al  = lds[buf][0];
        const u16* Bl  = lds[buf][1];
        short8 bfr[4][2], a01[2][2], a23[2][2], a45[2][2], a67[2][2];

        // ---- phase 1: read all B + A[0:2) (12 b128); MFMA mf 0-1 ----
#pragma unroll
        for (int nf = 0; nf < 4; ++nf)
#pragma unroll
            for (int ks = 0; ks < 2; ++ks)
                bfr[nf][ks] = *(const short8*)&Bl[rdB0 + (nf * 2 + ks) * 512];
#pragma unroll
        for (int mf = 0; mf < 2; ++mf)
#pragma unroll
            for (int ks = 0; ks < 2; ++ks)
                a01[mf][ks] = *(const short8*)&Al[rdA0 + (mf * 2 + ks) * 512];
        __builtin_amdgcn_s_barrier();
        __builtin_amdgcn_s_setprio(1);
#pragma unroll
        for (int mf = 0; mf < 2; ++mf)
#pragma unroll
            for (int nf = 0; nf < 4; ++nf)
#pragma unroll
                for (int ks = 0; ks < 2; ++ks)
                    acc[mf][nf] = __builtin_amdgcn_mfma_f32_16x16x32_bf16(
                        a01[mf][ks], bfr[nf][ks], acc[mf][nf], 0, 0, 0);
        __builtin_amdgcn_s_setprio(0);
        __builtin_amdgcn_s_barrier();
        // all B(t) + A-X reads retired (consumed above) -> B-h0 stageable

        // ---- phase 2: read A[2:4); stage B-h0(t+2); MFMA mf 2-3 ----
#pragma unroll
        for (int mf = 0; mf < 2; ++mf)
#pragma unroll
            for (int ks = 0; ks < 2; ++ks)
                a23[mf][ks] = *(const short8*)&Al[rdA0 + ((mf + 2) * 2 + ks) * 512];
        if (pf) STAGE_B(buf, 0, kk2);
        __builtin_amdgcn_s_barrier();
        __builtin_amdgcn_s_setprio(1);
#pragma unroll
        for (int mf = 0; mf < 2; ++mf)
#pragma unroll
            for (int nf = 0; nf < 4; ++nf)
#pragma unroll
                for (int ks = 0; ks < 2; ++ks)
                    acc[mf + 2][nf] = __builtin_amdgcn_mfma_f32_16x16x32_bf16(
                        a23[mf][ks], bfr[nf][ks], acc[mf + 2][nf], 0, 0, 0);
        __builtin_amdgcn_s_setprio(0);
        __builtin_amdgcn_s_barrier();

        // ---- phase 3: read A[4:8) (8 b128); stage B-h1(t+2); MFMA mf 4-5 ----
#pragma unroll
        for (int mf = 0; mf < 2; ++mf)
#pragma unroll
            for (int ks = 0; ks < 2; ++ks) {
                a45[mf][ks] = *(const short8*)&Al[rdA0 + ((mf + 4) * 2 + ks) * 512];
                a67[mf][ks] = *(const short8*)&Al[rdA0 + ((mf + 6) * 2 + ks) * 512];
            }
        if (pf) STAGE_B(buf, 1, kk2);
        __builtin_amdgcn_s_barrier();
        __builtin_amdgcn_s_setprio(1);
#pragma unroll
        for (int mf = 0; mf < 2; ++mf)
#pragma unroll
            for (int nf = 0; nf < 4; ++nf)
#pragma unroll
                for (int ks = 0; ks < 2; ++ks)
                    acc[mf + 4][nf] = __builtin_amdgcn_mfma_f32_16x16x32_bf16(
                        a45[mf][ks], bfr[nf][ks], acc[mf + 4][nf], 0, 0, 0);
        __builtin_amdgcn_s_setprio(0);
        // a67 is consumed only in phase 4: force its ds_reads to retire before
        // the barrier that allows other waves to overwrite the A region.
        asm volatile("s_waitcnt lgkmcnt(0)" ::: "memory");
        __builtin_amdgcn_s_barrier();

        // ---- phase 4: stage A both units (t+2); MFMA mf 6-7; checkpoint ----
        if (pf) { STAGE_A(buf, 0, kk2); STAGE_A(buf, 1, kk2); }
        __builtin_amdgcn_s_barrier();
        __builtin_amdgcn_s_setprio(1);
#pragma unroll
        for (int mf = 0; mf < 2; ++mf)
#pragma unroll
            for (int nf = 0; nf < 4; ++nf)
#pragma unroll
                for (int ks = 0; ks < 2; ++ks)
                    acc[mf + 6][nf] = __builtin_amdgcn_mfma_f32_16x16x32_bf16(
                        a67[mf][ks], bfr[nf][ks], acc[mf + 6][nf], 0, 0, 0);
        __builtin_amdgcn_s_setprio(0);
        // counted checkpoint: leave exactly this iter's 8 stage-loads (tile
        // t+2) in flight; guarantees tile t+1 fully landed before next group.
        if (pf) asm volatile("s_waitcnt vmcnt(8)" ::: "memory");
        else    asm volatile("s_waitcnt vmcnt(0)" ::: "memory");
        __builtin_amdgcn_s_barrier();
    }
#undef STAGE_A
#undef STAGE_B

    // ---- epilogue: C/D layout col=lane&15, row=quad*4+reg ----
    if (!isV) {
#pragma unroll
        for (int mf = 0; mf < 8; ++mf) {
            int m = m0 + wm * 128 + mf * 16 + quad * 4;
#pragma unroll
            for (int nf = 0; nf < 4; ++nf) {
                int n = n0 + wn * 64 + nf * 16 + r16;
#pragma unroll
                for (int r = 0; r < 4; ++r)
                    qk[(m + r) * 2048 + n] = f2b(acc[mf][nf][r]);
            }
        }
    } else {
#pragma unroll
        for (int mf = 0; mf < 8; ++mf) {
            int mbase = m0 + wm * 128 + mf * 16 + quad * 4;   // 4-aligned
            int b = mbase >> 11;
            int s = mbase & 2047;
#pragma unroll
            for (int nf = 0; nf < 4; ++nf) {
                int d = n0 + wn * 64 + nf * 16 + r16;
                u16x4 o;
#pragma unroll
                for (int r = 0; r < 4; ++r) o[r] = f2b(acc[mf][nf][r]);
                *(u16x4*)(vt + (((b << 10) + d) * 2048 + s)) = o;
            }
        }
    }
}

// ---------------- BT-GEMM core (scores / pv, unchanged) --------------------
#define MT 128
#define NT 128
#define BKH 32
#define HSZ (MT * BKH)   // elems per half buffer = 4096

template <int TRANS, typename OutT>
__device__ __forceinline__ void gemm_core(
    u16* __restrict__ As, u16* __restrict__ Bs,
    const u16* __restrict__ Ab, int lda,
    const u16* __restrict__ Bb, int ldb,
    OutT* __restrict__ Cb, int ldc,
    int m0, int n0, int kbeg, int kend)
{
    const int tid  = threadIdx.x;
    const int lane = tid & 63;
    const int wave = tid >> 6;
    const int quad = lane >> 4;
    const int r16  = lane & 15;
    const int mw   = (wave >> 1) * 64;
    const int nw   = (wave & 1) * 64;

    const int c0 = tid, c1 = tid + 256;
    const int r0 = c0 >> 2, k0 = (c0 & 3) * 8;
    const int r1 = c1 >> 2, k1 = (c1 & 3) * 8;
    const int oa0 = (m0 + r0) * lda + k0;
    const int oa1 = (m0 + r1) * lda + k1;
    const int ob0 = (n0 + r0) * ldb + k0;
    const int ob1 = (n0 + r1) * ldb + k1;

    f32x4 acc[4][4] = {};

    for (int kk = kbeg; kk < kend; kk += 2 * BKH) {
        __syncthreads();
        gload_lds16(Ab + (kk + oa0),        &As[c0 * 8]);
        gload_lds16(Ab + (kk + oa1),        &As[c1 * 8]);
        gload_lds16(Ab + (kk + BKH + oa0),  &As[HSZ + c0 * 8]);
        gload_lds16(Ab + (kk + BKH + oa1),  &As[HSZ + c1 * 8]);
        gload_lds16(Bb + (kk + ob0),        &Bs[c0 * 8]);
        gload_lds16(Bb + (kk + ob1),        &Bs[c1 * 8]);
        gload_lds16(Bb + (kk + BKH + ob0),  &Bs[HSZ + c0 * 8]);
        gload_lds16(Bb + (kk + BKH + ob1),  &Bs[HSZ + c1 * 8]);
        __syncthreads();

#pragma unroll
        for (int h = 0; h < 2; h++) {
            short8 af[4], bf[4];
#pragma unroll
            for (int i = 0; i < 4; i++)
                af[i] = *(const short8*)&As[h * HSZ + (mw + i * 16 + r16) * BKH + quad * 8];
#pragma unroll
            for (int j = 0; j < 4; j++)
                bf[j] = *(const short8*)&Bs[h * HSZ + (nw + j * 16 + r16) * BKH + quad * 8];
#pragma unroll
            for (int i = 0; i < 4; i++)
#pragma unroll
                for (int j = 0; j < 4; j++)
                    acc[i][j] = __builtin_amdgcn_mfma_f32_16x16x32_bf16(af[i], bf[j], acc[i][j], 0, 0, 0);
        }
    }

    if (TRANS == 0) {
#pragma unroll
        for (int i = 0; i < 4; i++)
#pragma unroll
            for (int j = 0; j < 4; j++)
#pragma unroll
                for (int r = 0; r < 4; r++) {
                    int m = m0 + mw + i * 16 + quad * 4 + r;
                    int n = n0 + nw + j * 16 + r16;
                    store_elem(&Cb[(long long)m * ldc + n], acc[i][j][r]);
                }
    } else {
#pragma unroll
        for (int i = 0; i < 4; i++)
#pragma unroll
            for (int j = 0; j < 4; j++) {
                int mbase = m0 + mw + i * 16 + quad * 4;
                int d     = n0 + nw + j * 16 + r16;
                int b     = mbase >> 11;
                int s     = mbase & 2047;
                u16x4 o;
#pragma unroll
                for (int r = 0; r < 4; r++) o[r] = f2b(acc[i][j][r]);
                *(u16x4*)((u16*)Cb + (((b << 10) + d) * 2048 + s)) = o;
            }
    }
}

__global__ __launch_bounds__(256, 4) void gemm_scores(
    const u16* __restrict__ qk, u16* __restrict__ sc) {
    __shared__ __align__(16) u16 As[2 * HSZ];
    __shared__ __align__(16) u16 Bs[2 * HSZ];
    int t = blockIdx.x;
    float ff = sqrtf(8.0f * t + 1.0f);
    int m = (int)((ff - 1.0f) * 0.5f);
    while ((m + 1) * (m + 2) / 2 <= t) m++;
    while (m * (m + 1) / 2 > t) m--;
    int m0 = m * MT;
    int n0 = (t - m * (m + 1) / 2) * NT;
    const u16* Ab = qk + (long long)blockIdx.z * 2048 * 2048;
    const u16* Bb = Ab + 1024;
    u16* Cb = sc + (long long)blockIdx.z * 2048 * 2048;
    gemm_core<0, u16>(As, Bs, Ab, 2048, Bb, 2048, Cb, 2048, m0, n0, 0, 1024);
}

// PV split-K, longest-first schedule: per batch 192 units.
__global__ __launch_bounds__(256, 4) void gemm_pv(
    const u16* __restrict__ P, const u16* __restrict__ vt,
    float* __restrict__ out, float* __restrict__ part)
{
    __shared__ __align__(16) u16 As[2 * HSZ];
    __shared__ __align__(16) u16 Bs[2 * HSZ];
    const int bid = blockIdx.x;
    int m, chunk, n;
    if (bid < 80) {                       // K = 1024 class
        int q = bid >> 3; n = bid & 7;
        if (q < 9) { m = 7 + q; chunk = 0; } else { m = 15; chunk = 1; }
    } else {                              // K = s*128, s = 7..1
        int r = bid - 80; int s = 7 - (r >> 4); int t = r & 15;
        n = t & 7;
        if (t < 8) { m = s - 1; chunk = 0; } else { m = s + 7; chunk = 1; }
    }
    const int m0 = m * MT, n0 = n * NT;
    const int kbeg = chunk ? 1024 : 0;
    const int kend = chunk ? (m0 + MT) : min(1024, m0 + MT);
    const int b = blockIdx.z;

    const u16* Ab = P  + (long long)b * 2048 * 2048;
    const u16* Bb = vt + (long long)b * 1024 * 2048;
    float* Cb = (chunk == 0)
        ? out  + (long long)b * 2097152
        : part + (long long)b * 1048576 - 1024LL * 1024;
    gemm_core<0, float>(As, Bs, Ab, 2048, Bb, 2048, Cb, 1024, m0, n0, kbeg, kend);
}

__global__ __launch_bounds__(256) void pv_combine(float* __restrict__ out,
                                                  const float* __restrict__ part) {
    long long idx = ((long long)blockIdx.x * 256 + threadIdx.x) * 8;
    long long bb = idx >> 20;
    long long j  = idx & 1048575;
    float* o = out + bb * 2097152 + 1048576 + j;
    const float* p = part + bb * 1048576 + j;
    float4 o0 = *(float4*)o, o1 = *(float4*)(o + 4);
    float4 p0 = *(const float4*)p, p1 = *(const float4*)(p + 4);
    o0.x += p0.x; o0.y += p0.y; o0.z += p0.z; o0.w += p0.w;
    o1.x += p1.x; o1.y += p1.y; o1.z += p1.z; o1.w += p1.w;
    *(float4*)o = o0; *(float4*)(o + 4) = o1;
}

// ---------------- single-pass causal softmax (bf16 in -> bf16 P) -----------
__global__ __launch_bounds__(256) void softmax_kernel(const u16* __restrict__ sc,
                                                      u16* __restrict__ P) {
    const int S = 2048;
    int row = blockIdx.x;            // b*S + i
    int i   = row & (S - 1);
    int n   = i + 1;
    int kendr = (i & ~127) + 128;
    const u16* srow = sc + (long long)row * S;
    u16*       prow = P  + (long long)row * S;

    int j0 = threadIdx.x * 8;
    u16x8 raw = {};
    if (j0 <= i) raw = *(const u16x8*)(srow + j0);
    float v[8];
#pragma unroll
    for (int e = 0; e < 8; e++) v[e] = (j0 + e < n) ? b2f(raw[e]) : -1e30f;

    __shared__ float red[8];
    float lmax = v[0];
#pragma unroll
    for (int e = 1; e < 8; e++) lmax = fmaxf(lmax, v[e]);
    for (int o = 32; o > 0; o >>= 1) lmax = fmaxf(lmax, __shfl_xor(lmax, o, 64));
    int wid = threadIdx.x >> 6;
    if ((threadIdx.x & 63) == 0) red[wid] = lmax;
    __syncthreads();
    float Mx = fmaxf(fmaxf(red[0], red[1]), fmaxf(red[2], red[3]));

    const float C = 0.045112384f;
    float ev[8];
    float lsum = 0.f;
#pragma unroll
    for (int e = 0; e < 8; e++) {
        ev[e] = (j0 + e < n) ? exp2f((v[e] - Mx) * C) : 0.f;
        lsum += ev[e];
    }
    for (int o = 32; o > 0; o >>= 1) lsum += __shfl_xor(lsum, o, 64);
    if ((threadIdx.x & 63) == 0) red[4 + wid] = lsum;
    __syncthreads();
    float inv = 1.0f / (red[4] + red[5] + red[6] + red[7]);

    if (j0 < kendr) {
        u16x8 o8;
#pragma unroll
        for (int e = 0; e < 8; e++) o8[e] = f2b(ev[e] * inv);
        *(u16x8*)(prow + j0) = o8;
    }
}

extern "C" void kernel_launch(void* const* d_in, const int* in_sizes, int n_in,
                              void* d_out, int out_size, void* d_ws, size_t ws_size,
                              hipStream_t stream) {
    const float* x  = (const float*)d_in[0];
    const float* wq = (const float*)d_in[1];
    const float* wk = (const float*)d_in[2];
    const float* wv = (const float*)d_in[3];
    float* out = (float*)d_out;

    char* ws = (char*)d_ws;
    // layout: xb 16M | wb 6M | qk 32M | sc 32M | P 32M | vt 16M | part 16M
    u16*   xb   = (u16*)(ws);
    u16*   wb   = (u16*)(ws + 16777216LL);
    u16*   qk   = (u16*)(ws + 23068672LL);
    u16*   sc   = (u16*)(ws + 56623104LL);
    u16*   P    = (u16*)(ws + 90177536LL);
    u16*   vt   = (u16*)(ws + 123731968LL);
    float* part = (float*)(ws + 140509184LL);   // total 157,286,400 bytes

    // 1. casts (x + 3 weights, one dispatch)
    cast_all_kernel<<<11264, 256, 0, stream>>>(x, wq, wk, wv, xb);

    // 2. QKV projection, 256^2 8-phase (V stored transposed; Q,K packed)
    gemm_qkv256<<<384, 512, 0, stream>>>(xb, wb, qk, vt);

    // 3. scores_b = Q_b K_b^T -> bf16, triangular tiles only (136/batch)
    gemm_scores<<<dim3(136, 1, 4), 256, 0, stream>>>(qk, sc);

    // 4. single-pass causal softmax -> P bf16
    softmax_kernel<<<8192, 256, 0, stream>>>(sc, P);

    // 5. PV split-K + combine
    gemm_pv<<<dim3(192, 1, 4), 256, 0, stream>>>(P, vt, out, part);
    pv_combine<<<2048, 256, 0, stream>>>(out, part);
}

// Round 2
// 253.337 us; speedup vs baseline: 1.0122x; 1.0122x over previous
//
#include <hip/hip_runtime.h>
#include <hip/hip_bf16.h>

// Causal attention, B=4 S=2048 E=1024 D=1024, fp32 in/out.
// Round 10: revert qkv to the proven r8 128^2 m97-structure core (the 256^2
// 8-phase port was per-CU faster but lost 33% to a 384-block/1-block-per-CU
// grid tail -> net regression). qkv now launches as TWO dispatches (Q|K then
// V) so the rocprof top-5 threshold drops to ~42us and exposes scores/pv.
// softmax rebalanced: pair row i with row 2047-i (constant work per block).

typedef unsigned short u16;
typedef __attribute__((ext_vector_type(4))) u16   u16x4;
typedef __attribute__((ext_vector_type(8))) u16   u16x8;
typedef __attribute__((ext_vector_type(8))) short short8;
typedef __attribute__((ext_vector_type(4))) float f32x4;
typedef __attribute__((ext_vector_type(4))) int   i32x4;

__device__ inline u16 f2b(float v) {
    __hip_bfloat16 b = __float2bfloat16(v);
    return *reinterpret_cast<u16*>(&b);
}
__device__ inline float b2f(u16 v) {
    unsigned int u = ((unsigned int)v) << 16;
    return *reinterpret_cast<float*>(&u);
}

template <typename T> __device__ inline void store_elem(T* p, float v);
template <> __device__ inline void store_elem<float>(float* p, float v) { *p = v; }
template <> __device__ inline void store_elem<u16>(u16* p, float v)     { *p = f2b(v); }

// async global->LDS 16B per lane; LDS dest must be wave-uniform base + lane*16
__device__ inline void gload_lds16(const u16* g, u16* l) {
    __builtin_amdgcn_global_load_lds(
        (const __attribute__((address_space(1))) void*)g,
        (__attribute__((address_space(3))) void*)l, 16, 0, 0);
}

// ---------------- merged fp32 -> bf16 cast: [x | wq | wk | wv] -------------
__global__ __launch_bounds__(256) void cast_all_kernel(
    const float* __restrict__ x,  const float* __restrict__ wq,
    const float* __restrict__ wk, const float* __restrict__ wv,
    u16* __restrict__ dst) {
    int q = blockIdx.x * 256 + threadIdx.x;     // quad index, 2883584 total
    const float* src;
    int sidx;
    if (q < 2097152) { src = x; sidx = q * 4; }
    else {
        int qq = q - 2097152;
        int w  = qq >> 18;                      // 262144 quads per weight
        sidx   = (qq & 262143) * 4;
        src    = (w == 0) ? wq : (w == 1) ? wk : wv;
    }
    float4 v = *(const float4*)(src + sidx);
    u16x4 o;
    o.x = f2b(v.x); o.y = f2b(v.y); o.z = f2b(v.z); o.w = f2b(v.w);
    *(u16x4*)(dst + q * 4) = o;
}

// ---------------- BT-GEMM core -----------------------------------------------
#define MT 128
#define NT 128
#define BKH 32
#define HSZ (MT * BKH)   // elems per half buffer = 4096

// As/Bs are caller-provided LDS (2*HSZ each) so multiple instantiations in
// one kernel share a single allocation.
// TRANS=0: C[m][n] = val (OutT). TRANS=1: transposed bf16 store into
// vt[b][d][s] (Cb = vt base, n0 = d base, b/s derived from m).
template <int TRANS, typename OutT>
__device__ __forceinline__ void gemm_core(
    u16* __restrict__ As, u16* __restrict__ Bs,
    const u16* __restrict__ Ab, int lda,
    const u16* __restrict__ Bb, int ldb,
    OutT* __restrict__ Cb, int ldc,
    int m0, int n0, int kbeg, int kend)
{
    const int tid  = threadIdx.x;
    const int lane = tid & 63;
    const int wave = tid >> 6;
    const int quad = lane >> 4;
    const int r16  = lane & 15;
    const int mw   = (wave >> 1) * 64;
    const int nw   = (wave & 1) * 64;

    const int c0 = tid, c1 = tid + 256;
    const int r0 = c0 >> 2, k0 = (c0 & 3) * 8;
    const int r1 = c1 >> 2, k1 = (c1 & 3) * 8;
    const int oa0 = (m0 + r0) * lda + k0;
    const int oa1 = (m0 + r1) * lda + k1;
    const int ob0 = (n0 + r0) * ldb + k0;
    const int ob1 = (n0 + r1) * ldb + k1;

    f32x4 acc[4][4] = {};

    for (int kk = kbeg; kk < kend; kk += 2 * BKH) {
        __syncthreads();
        gload_lds16(Ab + (kk + oa0),        &As[c0 * 8]);
        gload_lds16(Ab + (kk + oa1),        &As[c1 * 8]);
        gload_lds16(Ab + (kk + BKH + oa0),  &As[HSZ + c0 * 8]);
        gload_lds16(Ab + (kk + BKH + oa1),  &As[HSZ + c1 * 8]);
        gload_lds16(Bb + (kk + ob0),        &Bs[c0 * 8]);
        gload_lds16(Bb + (kk + ob1),        &Bs[c1 * 8]);
        gload_lds16(Bb + (kk + BKH + ob0),  &Bs[HSZ + c0 * 8]);
        gload_lds16(Bb + (kk + BKH + ob1),  &Bs[HSZ + c1 * 8]);
        __syncthreads();

#pragma unroll
        for (int h = 0; h < 2; h++) {
            short8 af[4], bf[4];
#pragma unroll
            for (int i = 0; i < 4; i++)
                af[i] = *(const short8*)&As[h * HSZ + (mw + i * 16 + r16) * BKH + quad * 8];
#pragma unroll
            for (int j = 0; j < 4; j++)
                bf[j] = *(const short8*)&Bs[h * HSZ + (nw + j * 16 + r16) * BKH + quad * 8];
#pragma unroll
            for (int i = 0; i < 4; i++)
#pragma unroll
                for (int j = 0; j < 4; j++)
                    acc[i][j] = __builtin_amdgcn_mfma_f32_16x16x32_bf16(af[i], bf[j], acc[i][j], 0, 0, 0);
        }
    }

    // epilogue: C/D layout col=lane&15, row=quad*4+reg
    if (TRANS == 0) {
#pragma unroll
        for (int i = 0; i < 4; i++)
#pragma unroll
            for (int j = 0; j < 4; j++)
#pragma unroll
                for (int r = 0; r < 4; r++) {
                    int m = m0 + mw + i * 16 + quad * 4 + r;
                    int n = n0 + nw + j * 16 + r16;
                    store_elem(&Cb[(long long)m * ldc + n], acc[i][j][r]);
                }
    } else {
#pragma unroll
        for (int i = 0; i < 4; i++)
#pragma unroll
            for (int j = 0; j < 4; j++) {
                int mbase = m0 + mw + i * 16 + quad * 4;      // 4-aligned
                int d     = n0 + nw + j * 16 + r16;
                int b     = mbase >> 11;
                int s     = mbase & 2047;
                u16x4 o;
#pragma unroll
                for (int r = 0; r < 4; r++) o[r] = f2b(acc[i][j][r]);
                *(u16x4*)((u16*)Cb + (((b << 10) + d) * 2048 + s)) = o;
            }
    }
}

// QKV: [8192,1024] x [3072,1024]^T. bx<16 -> qk[8192,2048] (Q|K dense);
// bx>=16 -> V, stored transposed into vt[b][d][s]. bx0 lets the launcher
// split Q|K and V into separate dispatches (profiling visibility + both are
// independent outputs).
__global__ __launch_bounds__(256, 4) void gemm_qkv(
    const u16* __restrict__ xb, const u16* __restrict__ wb,
    u16* __restrict__ qk, u16* __restrict__ vt, int bx0) {
    __shared__ __align__(16) u16 As[2 * HSZ];
    __shared__ __align__(16) u16 Bs[2 * HSZ];
    int bx = blockIdx.x + bx0, m0 = blockIdx.y * MT;
    if (bx < 16)
        gemm_core<0, u16>(As, Bs, xb, 1024, wb, 1024, qk, 2048,
                          m0, bx * 128, 0, 1024);
    else
        gemm_core<1, u16>(As, Bs, xb, 1024, wb + 2048 * 1024, 1024, vt, 2048,
                          m0, (bx - 16) * 128, 0, 1024);
}

__global__ __launch_bounds__(256, 4) void gemm_scores(
    const u16* __restrict__ qk, u16* __restrict__ sc) {
    __shared__ __align__(16) u16 As[2 * HSZ];
    __shared__ __align__(16) u16 Bs[2 * HSZ];
    // per batch: Q[2048,1024(ld2048)] x K^T -> sc[2048,2048], lower-tri tiles
    int t = blockIdx.x;
    float ff = sqrtf(8.0f * t + 1.0f);
    int m = (int)((ff - 1.0f) * 0.5f);
    while ((m + 1) * (m + 2) / 2 <= t) m++;
    while (m * (m + 1) / 2 > t) m--;
    int m0 = m * MT;
    int n0 = (t - m * (m + 1) / 2) * NT;
    const u16* Ab = qk + (long long)blockIdx.z * 2048 * 2048;
    const u16* Bb = Ab + 1024;
    u16* Cb = sc + (long long)blockIdx.z * 2048 * 2048;
    gemm_core<0, u16>(As, Bs, Ab, 2048, Bb, 2048, Cb, 2048, m0, n0, 0, 1024);
}

// PV split-K, longest-first schedule: per batch 192 units (see round 5).
__global__ __launch_bounds__(256, 4) void gemm_pv(
    const u16* __restrict__ P, const u16* __restrict__ vt,
    float* __restrict__ out, float* __restrict__ part)
{
    __shared__ __align__(16) u16 As[2 * HSZ];
    __shared__ __align__(16) u16 Bs[2 * HSZ];
    const int bid = blockIdx.x;
    int m, chunk, n;
    if (bid < 80) {                       // K = 1024 class
        int q = bid >> 3; n = bid & 7;
        if (q < 9) { m = 7 + q; chunk = 0; } else { m = 15; chunk = 1; }
    } else {                              // K = s*128, s = 7..1
        int r = bid - 80; int s = 7 - (r >> 4); int t = r & 15;
        n = t & 7;
        if (t < 8) { m = s - 1; chunk = 0; } else { m = s + 7; chunk = 1; }
    }
    const int m0 = m * MT, n0 = n * NT;
    const int kbeg = chunk ? 1024 : 0;
    const int kend = chunk ? (m0 + MT) : min(1024, m0 + MT);
    const int b = blockIdx.z;

    const u16* Ab = P  + (long long)b * 2048 * 2048;
    const u16* Bb = vt + (long long)b * 1024 * 2048;
    float* Cb = (chunk == 0)
        ? out  + (long long)b * 2097152
        : part + (long long)b * 1048576 - 1024LL * 1024;   // rows (m-1024)
    gemm_core<0, float>(As, Bs, Ab, 2048, Bb, 2048, Cb, 1024, m0, n0, kbeg, kend);
}

// combine: out[b][1024+r][c] += part[b][r][c]
__global__ __launch_bounds__(256) void pv_combine(float* __restrict__ out,
                                                  const float* __restrict__ part) {
    long long idx = ((long long)blockIdx.x * 256 + threadIdx.x) * 8;
    long long bb = idx >> 20;
    long long j  = idx & 1048575;
    float* o = out + bb * 2097152 + 1048576 + j;
    const float* p = part + bb * 1048576 + j;
    float4 o0 = *(float4*)o, o1 = *(float4*)(o + 4);
    float4 p0 = *(const float4*)p, p1 = *(const float4*)(p + 4);
    o0.x += p0.x; o0.y += p0.y; o0.z += p0.z; o0.w += p0.w;
    o1.x += p1.x; o1.y += p1.y; o1.z += p1.z; o1.w += p1.w;
    *(float4*)o = o0; *(float4*)(o + 4) = o1;
}

// ---------------- single-pass causal softmax (bf16 in -> bf16 P) -----------
// triangle-trimmed: loads only j<=i, writes only up to the row's 128-aligned
// tile boundary (PV never reads past kend_row = (i & ~127) + 128).
__device__ __forceinline__ void softmax_row(const u16* __restrict__ sc,
                                            u16* __restrict__ P, int row,
                                            float* __restrict__ red) {
    const int S = 2048;
    int i   = row & (S - 1);
    int n   = i + 1;
    int kendr = (i & ~127) + 128;
    const u16* srow = sc + (long long)row * S;
    u16*       prow = P  + (long long)row * S;

    int j0 = threadIdx.x * 8;
    u16x8 raw = {};
    if (j0 <= i) raw = *(const u16x8*)(srow + j0);
    float v[8];
#pragma unroll
    for (int e = 0; e < 8; e++) v[e] = (j0 + e < n) ? b2f(raw[e]) : -1e30f;

    float lmax = v[0];
#pragma unroll
    for (int e = 1; e < 8; e++) lmax = fmaxf(lmax, v[e]);
    for (int o = 32; o > 0; o >>= 1) lmax = fmaxf(lmax, __shfl_xor(lmax, o, 64));
    int wid = threadIdx.x >> 6;
    if ((threadIdx.x & 63) == 0) red[wid] = lmax;
    __syncthreads();
    float Mx = fmaxf(fmaxf(red[0], red[1]), fmaxf(red[2], red[3]));

    // exp((s-Mx)/32) = exp2((s-Mx) * (1/(32 ln2)))
    const float C = 0.045112384f;
    float ev[8];
    float lsum = 0.f;
#pragma unroll
    for (int e = 0; e < 8; e++) {
        ev[e] = (j0 + e < n) ? exp2f((v[e] - Mx) * C) : 0.f;
        lsum += ev[e];
    }
    for (int o = 32; o > 0; o >>= 1) lsum += __shfl_xor(lsum, o, 64);
    if ((threadIdx.x & 63) == 0) red[4 + wid] = lsum;
    __syncthreads();
    float inv = 1.0f / (red[4] + red[5] + red[6] + red[7]);

    if (j0 < kendr) {
        u16x8 o8;
#pragma unroll
        for (int e = 0; e < 8; e++) o8[e] = f2b(ev[e] * inv);
        *(u16x8*)(prow + j0) = o8;
    }
}

// paired rows i and 2047-i -> constant ~2049 useful elems per block
__global__ __launch_bounds__(256) void softmax_kernel(const u16* __restrict__ sc,
                                                      u16* __restrict__ P) {
    __shared__ float red[8];
    int i = blockIdx.x;          // 0..1023
    int z = blockIdx.z;          // batch
    softmax_row(sc, P, z * 2048 + (2047 - i), red);
    softmax_row(sc, P, z * 2048 + i, red);
}

extern "C" void kernel_launch(void* const* d_in, const int* in_sizes, int n_in,
                              void* d_out, int out_size, void* d_ws, size_t ws_size,
                              hipStream_t stream) {
    const float* x  = (const float*)d_in[0];
    const float* wq = (const float*)d_in[1];
    const float* wk = (const float*)d_in[2];
    const float* wv = (const float*)d_in[3];
    float* out = (float*)d_out;

    char* ws = (char*)d_ws;
    // layout: xb 16M | wb 6M | qk 32M | sc 32M | P 32M | vt 16M | part 16M
    u16*   xb   = (u16*)(ws);
    u16*   wb   = (u16*)(ws + 16777216LL);
    u16*   qk   = (u16*)(ws + 23068672LL);
    u16*   sc   = (u16*)(ws + 56623104LL);
    u16*   P    = (u16*)(ws + 90177536LL);
    u16*   vt   = (u16*)(ws + 123731968LL);
    float* part = (float*)(ws + 140509184LL);   // total 157,286,400 bytes

    // 1. casts (x + 3 weights, one dispatch)
    cast_all_kernel<<<11264, 256, 0, stream>>>(x, wq, wk, wv, xb);

    // 2. QKV projection, split into Q|K and V dispatches (independent outputs;
    //    also drops the rocprof top-5 threshold so scores/pv surface)
    gemm_qkv<<<dim3(16, 64, 1), 256, 0, stream>>>(xb, wb, qk, vt, 0);
    gemm_qkv<<<dim3(8, 64, 1), 256, 0, stream>>>(xb, wb, qk, vt, 16);

    // 3. scores_b = Q_b K_b^T -> bf16, triangular tiles only (136/batch)
    gemm_scores<<<dim3(136, 1, 4), 256, 0, stream>>>(qk, sc);

    // 4. single-pass causal softmax -> P bf16 (paired-row balanced)
    softmax_kernel<<<dim3(1024, 1, 4), 256, 0, stream>>>(sc, P);

    // 5. PV split-K + combine
    gemm_pv<<<dim3(192, 1, 4), 256, 0, stream>>>(P, vt, out, part);
    pv_combine<<<2048, 256, 0, stream>>>(out, part);
}

// Round 3
// 247.924 us; speedup vs baseline: 1.0343x; 1.0218x over previous
//
#include <hip/hip_runtime.h>
#include <hip/hip_bf16.h>

// Causal attention, B=4 S=2048 E=1024 D=1024, fp32 in/out.
// Round 11:
//  - QK projection moved to the (r9-verified) 256x256 8-phase core with grid
//    EXACTLY 256 blocks (32 m-panels x 8 n-panels) = 1 block/CU, no tail.
//    r9 measured 37.7us/round for this core; r10's 128^2 QK was 45us.
//  - V projection (512 blocks of the 128^2 core) merged INTO the scores
//    dispatch (544+512=1056 blocks ~ 4.1/CU, all co-resident): absorbs V's
//    serialized ~23us + one ~8us graph-node boundary.
//  - 6 dispatches total: cast, qk256, scores+V, softmax, pv, combine.

typedef unsigned short u16;
typedef __attribute__((ext_vector_type(4))) u16   u16x4;
typedef __attribute__((ext_vector_type(8))) u16   u16x8;
typedef __attribute__((ext_vector_type(8))) short short8;
typedef __attribute__((ext_vector_type(4))) float f32x4;
typedef __attribute__((ext_vector_type(4))) int   i32x4;

__device__ inline u16 f2b(float v) {
    __hip_bfloat16 b = __float2bfloat16(v);
    return *reinterpret_cast<u16*>(&b);
}
__device__ inline float b2f(u16 v) {
    unsigned int u = ((unsigned int)v) << 16;
    return *reinterpret_cast<float*>(&u);
}

template <typename T> __device__ inline void store_elem(T* p, float v);
template <> __device__ inline void store_elem<float>(float* p, float v) { *p = v; }
template <> __device__ inline void store_elem<u16>(u16* p, float v)     { *p = f2b(v); }

// async global->LDS 16B per lane; LDS dest must be wave-uniform base + lane*16
__device__ inline void gload_lds16(const u16* g, u16* l) {
    __builtin_amdgcn_global_load_lds(
        (const __attribute__((address_space(1))) void*)g,
        (__attribute__((address_space(3))) void*)l, 16, 0, 0);
}

// ---------------- merged fp32 -> bf16 cast: [x | wq | wk | wv] -------------
__global__ __launch_bounds__(256) void cast_all_kernel(
    const float* __restrict__ x,  const float* __restrict__ wq,
    const float* __restrict__ wk, const float* __restrict__ wv,
    u16* __restrict__ dst) {
    int q = blockIdx.x * 256 + threadIdx.x;     // quad index, 2883584 total
    const float* src;
    int sidx;
    if (q < 2097152) { src = x; sidx = q * 4; }
    else {
        int qq = q - 2097152;
        int w  = qq >> 18;                      // 262144 quads per weight
        sidx   = (qq & 262143) * 4;
        src    = (w == 0) ? wq : (w == 1) ? wk : wv;
    }
    float4 v = *(const float4*)(src + sidx);
    u16x4 o;
    o.x = f2b(v.x); o.y = f2b(v.y); o.z = f2b(v.z); o.w = f2b(v.w);
    *(u16x4*)(dst + q * 4) = o;
}

// ---------------- 256x256 8-phase QK GEMM ----------------------------------
// qk = xb[8192,1024] x wb[0:2048,1024]^T, dense bf16 store [8192,2048].
// Grid = 256 blocks (32 m x 8 n) = exactly 1 block/CU, single round.
__global__ __launch_bounds__(512) void gemm_qk256(
    const u16* __restrict__ xb, const u16* __restrict__ wb,
    u16* __restrict__ qk)
{
    __shared__ __align__(16) u16 lds[2][2][16384];   // [dbuf][A=0/B=1][256x64]

    const int tid  = threadIdx.x;
    const int lane = tid & 63;
    const int wave = tid >> 6;
    const int quad = lane >> 4;
    const int r16  = lane & 15;
    const int wm   = wave >> 2;   // 0..1  (M direction, 128 rows each)
    const int wn   = wave & 3;    // 0..3  (N direction, 64 cols each)

    int flat = blockIdx.x;                     // 0..255, 256 % 8 == 0
    int swz  = (flat & 7) * 32 + (flat >> 3);  // bijective XCD swizzle
    int m0   = (swz >> 3) * 256;
    const int n0 = (swz & 7) * 256;
    const u16* __restrict__ Ab = xb;
    const u16* __restrict__ Bb = wb;

    // --- staging precompute: linear LDS dest, inverse-swizzled global src ---
    int gA[2][2], gB[2][2], lA[2][2], lB[2][2];
    {
        const int cswz = ((lane & 3) * 8) ^ (((lane >> 5) & 1) << 4);
        const int rsub = lane >> 2;
#pragma unroll
        for (int u = 0; u < 2; ++u)
#pragma unroll
            for (int j = 0; j < 2; ++j) {
                int s   = j * 8 + wave;
                int sh  = s >> 1, cg = s & 1;
                int rgA = (sh & 3) + (sh >> 2) * 8 + u * 4;
                int rgB = sh + u * 8;
                int cl  = cg * 32 + cswz;
                gA[u][j] = (m0 + rgA * 16 + rsub) * 1024 + cl;
                gB[u][j] = (n0 + rgB * 16 + rsub) * 1024 + cl;
                lA[u][j] = (rgA * 2 + cg) * 512 + lane * 8;
                lB[u][j] = (rgB * 2 + cg) * 512 + lane * 8;
            }
    }

#define STAGE_A(BUF, U, KK) do { \
        gload_lds16(Ab + gA[U][0] + (KK), &lds[BUF][0][lA[U][0]]); \
        gload_lds16(Ab + gA[U][1] + (KK), &lds[BUF][0][lA[U][1]]); } while (0)
#define STAGE_B(BUF, U, KK) do { \
        gload_lds16(Bb + gB[U][0] + (KK), &lds[BUF][1][lB[U][0]]); \
        gload_lds16(Bb + gB[U][1] + (KK), &lds[BUF][1][lB[U][1]]); } while (0)

    // --- fragment read bases (same swizzle on the read side) ---
    const int cswr = (quad * 8) ^ ((r16 >> 3) << 4);
    const int rdA0 = wm * 16 * 512 + r16 * 32 + cswr;
    const int rdB0 = wn * 8  * 512 + r16 * 32 + cswr;

    f32x4 acc[8][4] = {};

    // prologue: tile0 -> buf0, tile1 -> buf1; wait tile0 (8 newest outstanding)
    STAGE_B(0, 0, 0);  STAGE_B(0, 1, 0);  STAGE_A(0, 0, 0);  STAGE_A(0, 1, 0);
    STAGE_B(1, 0, 64); STAGE_B(1, 1, 64); STAGE_A(1, 0, 64); STAGE_A(1, 1, 64);
    asm volatile("s_waitcnt vmcnt(8)" ::: "memory");
    __builtin_amdgcn_s_barrier();

    for (int t = 0; t < 16; ++t) {
        const int  buf = t & 1;
        const int  kk2 = t * 64 + 128;    // K offset of tile t+2 (same buffer)
        const bool pf  = (t < 14);
        const u16* Al  = lds[buf][0];
        const u16* Bl  = lds[buf][1];
        short8 bfr[4][2], a01[2][2], a23[2][2], a45[2][2], a67[2][2];

        // ---- phase 1: read all B + A[0:2) (12 b128); MFMA mf 0-1 ----
#pragma unroll
        for (int nf = 0; nf < 4; ++nf)
#pragma unroll
            for (int ks = 0; ks < 2; ++ks)
                bfr[nf][ks] = *(const short8*)&Bl[rdB0 + (nf * 2 + ks) * 512];
#pragma unroll
        for (int mf = 0; mf < 2; ++mf)
#pragma unroll
            for (int ks = 0; ks < 2; ++ks)
                a01[mf][ks] = *(const short8*)&Al[rdA0 + (mf * 2 + ks) * 512];
        __builtin_amdgcn_s_barrier();
        __builtin_amdgcn_s_setprio(1);
#pragma unroll
        for (int mf = 0; mf < 2; ++mf)
#pragma unroll
            for (int nf = 0; nf < 4; ++nf)
#pragma unroll
                for (int ks = 0; ks < 2; ++ks)
                    acc[mf][nf] = __builtin_amdgcn_mfma_f32_16x16x32_bf16(
                        a01[mf][ks], bfr[nf][ks], acc[mf][nf], 0, 0, 0);
        __builtin_amdgcn_s_setprio(0);
        __builtin_amdgcn_s_barrier();

        // ---- phase 2: read A[2:4); stage B-h0(t+2); MFMA mf 2-3 ----
#pragma unroll
        for (int mf = 0; mf < 2; ++mf)
#pragma unroll
            for (int ks = 0; ks < 2; ++ks)
                a23[mf][ks] = *(const short8*)&Al[rdA0 + ((mf + 2) * 2 + ks) * 512];
        if (pf) STAGE_B(buf, 0, kk2);
        __builtin_amdgcn_s_barrier();
        __builtin_amdgcn_s_setprio(1);
#pragma unroll
        for (int mf = 0; mf < 2; ++mf)
#pragma unroll
            for (int nf = 0; nf < 4; ++nf)
#pragma unroll
                for (int ks = 0; ks < 2; ++ks)
                    acc[mf + 2][nf] = __builtin_amdgcn_mfma_f32_16x16x32_bf16(
                        a23[mf][ks], bfr[nf][ks], acc[mf + 2][nf], 0, 0, 0);
        __builtin_amdgcn_s_setprio(0);
        __builtin_amdgcn_s_barrier();

        // ---- phase 3: read A[4:8) (8 b128); stage B-h1(t+2); MFMA mf 4-5 ----
#pragma unroll
        for (int mf = 0; mf < 2; ++mf)
#pragma unroll
            for (int ks = 0; ks < 2; ++ks) {
                a45[mf][ks] = *(const short8*)&Al[rdA0 + ((mf + 4) * 2 + ks) * 512];
                a67[mf][ks] = *(const short8*)&Al[rdA0 + ((mf + 6) * 2 + ks) * 512];
            }
        if (pf) STAGE_B(buf, 1, kk2);
        __builtin_amdgcn_s_barrier();
        __builtin_amdgcn_s_setprio(1);
#pragma unroll
        for (int mf = 0; mf < 2; ++mf)
#pragma unroll
            for (int nf = 0; nf < 4; ++nf)
#pragma unroll
                for (int ks = 0; ks < 2; ++ks)
                    acc[mf + 4][nf] = __builtin_amdgcn_mfma_f32_16x16x32_bf16(
                        a45[mf][ks], bfr[nf][ks], acc[mf + 4][nf], 0, 0, 0);
        __builtin_amdgcn_s_setprio(0);
        // a67 is consumed only in phase 4: retire its ds_reads before the
        // barrier that lets other waves overwrite the A region.
        asm volatile("s_waitcnt lgkmcnt(0)" ::: "memory");
        __builtin_amdgcn_s_barrier();

        // ---- phase 4: stage A both units (t+2); MFMA mf 6-7; checkpoint ----
        if (pf) { STAGE_A(buf, 0, kk2); STAGE_A(buf, 1, kk2); }
        __builtin_amdgcn_s_barrier();
        __builtin_amdgcn_s_setprio(1);
#pragma unroll
        for (int mf = 0; mf < 2; ++mf)
#pragma unroll
            for (int nf = 0; nf < 4; ++nf)
#pragma unroll
                for (int ks = 0; ks < 2; ++ks)
                    acc[mf + 6][nf] = __builtin_amdgcn_mfma_f32_16x16x32_bf16(
                        a67[mf][ks], bfr[nf][ks], acc[mf + 6][nf], 0, 0, 0);
        __builtin_amdgcn_s_setprio(0);
        // counted checkpoint: leave exactly this iter's 8 stage-loads (tile
        // t+2) in flight; guarantees tile t+1 fully landed before next group.
        if (pf) asm volatile("s_waitcnt vmcnt(8)" ::: "memory");
        else    asm volatile("s_waitcnt vmcnt(0)" ::: "memory");
        __builtin_amdgcn_s_barrier();
    }
#undef STAGE_A
#undef STAGE_B

    // ---- epilogue: C/D layout col=lane&15, row=quad*4+reg ----
#pragma unroll
    for (int mf = 0; mf < 8; ++mf) {
        int m = m0 + wm * 128 + mf * 16 + quad * 4;
#pragma unroll
        for (int nf = 0; nf < 4; ++nf) {
            int n = n0 + wn * 64 + nf * 16 + r16;
#pragma unroll
            for (int r = 0; r < 4; ++r)
                qk[(m + r) * 2048 + n] = f2b(acc[mf][nf][r]);
        }
    }
}

// ---------------- BT-GEMM core (scores / V / pv) ---------------------------
#define MT 128
#define NT 128
#define BKH 32
#define HSZ (MT * BKH)   // elems per half buffer = 4096

template <int TRANS, typename OutT>
__device__ __forceinline__ void gemm_core(
    u16* __restrict__ As, u16* __restrict__ Bs,
    const u16* __restrict__ Ab, int lda,
    const u16* __restrict__ Bb, int ldb,
    OutT* __restrict__ Cb, int ldc,
    int m0, int n0, int kbeg, int kend)
{
    const int tid  = threadIdx.x;
    const int lane = tid & 63;
    const int wave = tid >> 6;
    const int quad = lane >> 4;
    const int r16  = lane & 15;
    const int mw   = (wave >> 1) * 64;
    const int nw   = (wave & 1) * 64;

    const int c0 = tid, c1 = tid + 256;
    const int r0 = c0 >> 2, k0 = (c0 & 3) * 8;
    const int r1 = c1 >> 2, k1 = (c1 & 3) * 8;
    const int oa0 = (m0 + r0) * lda + k0;
    const int oa1 = (m0 + r1) * lda + k1;
    const int ob0 = (n0 + r0) * ldb + k0;
    const int ob1 = (n0 + r1) * ldb + k1;

    f32x4 acc[4][4] = {};

    for (int kk = kbeg; kk < kend; kk += 2 * BKH) {
        __syncthreads();
        gload_lds16(Ab + (kk + oa0),        &As[c0 * 8]);
        gload_lds16(Ab + (kk + oa1),        &As[c1 * 8]);
        gload_lds16(Ab + (kk + BKH + oa0),  &As[HSZ + c0 * 8]);
        gload_lds16(Ab + (kk + BKH + oa1),  &As[HSZ + c1 * 8]);
        gload_lds16(Bb + (kk + ob0),        &Bs[c0 * 8]);
        gload_lds16(Bb + (kk + ob1),        &Bs[c1 * 8]);
        gload_lds16(Bb + (kk + BKH + ob0),  &Bs[HSZ + c0 * 8]);
        gload_lds16(Bb + (kk + BKH + ob1),  &Bs[HSZ + c1 * 8]);
        __syncthreads();

#pragma unroll
        for (int h = 0; h < 2; h++) {
            short8 af[4], bf[4];
#pragma unroll
            for (int i = 0; i < 4; i++)
                af[i] = *(const short8*)&As[h * HSZ + (mw + i * 16 + r16) * BKH + quad * 8];
#pragma unroll
            for (int j = 0; j < 4; j++)
                bf[j] = *(const short8*)&Bs[h * HSZ + (nw + j * 16 + r16) * BKH + quad * 8];
#pragma unroll
            for (int i = 0; i < 4; i++)
#pragma unroll
                for (int j = 0; j < 4; j++)
                    acc[i][j] = __builtin_amdgcn_mfma_f32_16x16x32_bf16(af[i], bf[j], acc[i][j], 0, 0, 0);
        }
    }

    // epilogue: C/D layout col=lane&15, row=quad*4+reg
    if (TRANS == 0) {
#pragma unroll
        for (int i = 0; i < 4; i++)
#pragma unroll
            for (int j = 0; j < 4; j++)
#pragma unroll
                for (int r = 0; r < 4; r++) {
                    int m = m0 + mw + i * 16 + quad * 4 + r;
                    int n = n0 + nw + j * 16 + r16;
                    store_elem(&Cb[(long long)m * ldc + n], acc[i][j][r]);
                }
    } else {
#pragma unroll
        for (int i = 0; i < 4; i++)
#pragma unroll
            for (int j = 0; j < 4; j++) {
                int mbase = m0 + mw + i * 16 + quad * 4;      // 4-aligned
                int d     = n0 + nw + j * 16 + r16;
                int b     = mbase >> 11;
                int s     = mbase & 2047;
                u16x4 o;
#pragma unroll
                for (int r = 0; r < 4; r++) o[r] = f2b(acc[i][j][r]);
                *(u16x4*)((u16*)Cb + (((b << 10) + d) * 2048 + s)) = o;
            }
    }
}

// scores (544 blocks) + V projection (512 blocks) in one dispatch.
// bid < 544: per-batch lower-tri tile of Q K^T. bid >= 544: V gemm with
// transposed store into vt[b][d][s].
__global__ __launch_bounds__(256, 4) void gemm_sv(
    const u16* __restrict__ qk, u16* __restrict__ sc,
    const u16* __restrict__ xb, const u16* __restrict__ wb,
    u16* __restrict__ vt) {
    __shared__ __align__(16) u16 As[2 * HSZ];
    __shared__ __align__(16) u16 Bs[2 * HSZ];
    int bid = blockIdx.x;
    if (bid < 544) {
        int z = bid / 136;
        int t = bid - z * 136;
        float ff = sqrtf(8.0f * t + 1.0f);
        int m = (int)((ff - 1.0f) * 0.5f);
        while ((m + 1) * (m + 2) / 2 <= t) m++;
        while (m * (m + 1) / 2 > t) m--;
        int m0 = m * MT;
        int n0 = (t - m * (m + 1) / 2) * NT;
        const u16* Ab = qk + (long long)z * 2048 * 2048;
        const u16* Bb = Ab + 1024;
        u16* Cb = sc + (long long)z * 2048 * 2048;
        gemm_core<0, u16>(As, Bs, Ab, 2048, Bb, 2048, Cb, 2048, m0, n0, 0, 1024);
    } else {
        int vb = bid - 544;
        int bx = vb & 7;
        int m0 = (vb >> 3) * MT;
        gemm_core<1, u16>(As, Bs, xb, 1024, wb + 2048 * 1024, 1024, vt, 2048,
                          m0, bx * 128, 0, 1024);
    }
}

// PV split-K, longest-first schedule: per batch 192 units.
__global__ __launch_bounds__(256, 4) void gemm_pv(
    const u16* __restrict__ P, const u16* __restrict__ vt,
    float* __restrict__ out, float* __restrict__ part)
{
    __shared__ __align__(16) u16 As[2 * HSZ];
    __shared__ __align__(16) u16 Bs[2 * HSZ];
    const int bid = blockIdx.x;
    int m, chunk, n;
    if (bid < 80) {                       // K = 1024 class
        int q = bid >> 3; n = bid & 7;
        if (q < 9) { m = 7 + q; chunk = 0; } else { m = 15; chunk = 1; }
    } else {                              // K = s*128, s = 7..1
        int r = bid - 80; int s = 7 - (r >> 4); int t = r & 15;
        n = t & 7;
        if (t < 8) { m = s - 1; chunk = 0; } else { m = s + 7; chunk = 1; }
    }
    const int m0 = m * MT, n0 = n * NT;
    const int kbeg = chunk ? 1024 : 0;
    const int kend = chunk ? (m0 + MT) : min(1024, m0 + MT);
    const int b = blockIdx.z;

    const u16* Ab = P  + (long long)b * 2048 * 2048;
    const u16* Bb = vt + (long long)b * 1024 * 2048;
    float* Cb = (chunk == 0)
        ? out  + (long long)b * 2097152
        : part + (long long)b * 1048576 - 1024LL * 1024;   // rows (m-1024)
    gemm_core<0, float>(As, Bs, Ab, 2048, Bb, 2048, Cb, 1024, m0, n0, kbeg, kend);
}

// combine: out[b][1024+r][c] += part[b][r][c]
__global__ __launch_bounds__(256) void pv_combine(float* __restrict__ out,
                                                  const float* __restrict__ part) {
    long long idx = ((long long)blockIdx.x * 256 + threadIdx.x) * 8;
    long long bb = idx >> 20;
    long long j  = idx & 1048575;
    float* o = out + bb * 2097152 + 1048576 + j;
    const float* p = part + bb * 1048576 + j;
    float4 o0 = *(float4*)o, o1 = *(float4*)(o + 4);
    float4 p0 = *(const float4*)p, p1 = *(const float4*)(p + 4);
    o0.x += p0.x; o0.y += p0.y; o0.z += p0.z; o0.w += p0.w;
    o1.x += p1.x; o1.y += p1.y; o1.z += p1.z; o1.w += p1.w;
    *(float4*)o = o0; *(float4*)(o + 4) = o1;
}

// ---------------- single-pass causal softmax (bf16 in -> bf16 P) -----------
__device__ __forceinline__ void softmax_row(const u16* __restrict__ sc,
                                            u16* __restrict__ P, int row,
                                            float* __restrict__ red) {
    const int S = 2048;
    int i   = row & (S - 1);
    int n   = i + 1;
    int kendr = (i & ~127) + 128;
    const u16* srow = sc + (long long)row * S;
    u16*       prow = P  + (long long)row * S;

    int j0 = threadIdx.x * 8;
    u16x8 raw = {};
    if (j0 <= i) raw = *(const u16x8*)(srow + j0);
    float v[8];
#pragma unroll
    for (int e = 0; e < 8; e++) v[e] = (j0 + e < n) ? b2f(raw[e]) : -1e30f;

    float lmax = v[0];
#pragma unroll
    for (int e = 1; e < 8; e++) lmax = fmaxf(lmax, v[e]);
    for (int o = 32; o > 0; o >>= 1) lmax = fmaxf(lmax, __shfl_xor(lmax, o, 64));
    int wid = threadIdx.x >> 6;
    if ((threadIdx.x & 63) == 0) red[wid] = lmax;
    __syncthreads();
    float Mx = fmaxf(fmaxf(red[0], red[1]), fmaxf(red[2], red[3]));

    // exp((s-Mx)/32) = exp2((s-Mx) * (1/(32 ln2)))
    const float C = 0.045112384f;
    float ev[8];
    float lsum = 0.f;
#pragma unroll
    for (int e = 0; e < 8; e++) {
        ev[e] = (j0 + e < n) ? exp2f((v[e] - Mx) * C) : 0.f;
        lsum += ev[e];
    }
    for (int o = 32; o > 0; o >>= 1) lsum += __shfl_xor(lsum, o, 64);
    if ((threadIdx.x & 63) == 0) red[4 + wid] = lsum;
    __syncthreads();
    float inv = 1.0f / (red[4] + red[5] + red[6] + red[7]);

    if (j0 < kendr) {
        u16x8 o8;
#pragma unroll
        for (int e = 0; e < 8; e++) o8[e] = f2b(ev[e] * inv);
        *(u16x8*)(prow + j0) = o8;
    }
}

// paired rows i and 2047-i -> constant ~2049 useful elems per block
__global__ __launch_bounds__(256) void softmax_kernel(const u16* __restrict__ sc,
                                                      u16* __restrict__ P) {
    __shared__ float red[8];
    int i = blockIdx.x;          // 0..1023
    int z = blockIdx.z;          // batch
    softmax_row(sc, P, z * 2048 + (2047 - i), red);
    softmax_row(sc, P, z * 2048 + i, red);
}

extern "C" void kernel_launch(void* const* d_in, const int* in_sizes, int n_in,
                              void* d_out, int out_size, void* d_ws, size_t ws_size,
                              hipStream_t stream) {
    const float* x  = (const float*)d_in[0];
    const float* wq = (const float*)d_in[1];
    const float* wk = (const float*)d_in[2];
    const float* wv = (const float*)d_in[3];
    float* out = (float*)d_out;

    char* ws = (char*)d_ws;
    // layout: xb 16M | wb 6M | qk 32M | sc 32M | P 32M | vt 16M | part 16M
    u16*   xb   = (u16*)(ws);
    u16*   wb   = (u16*)(ws + 16777216LL);
    u16*   qk   = (u16*)(ws + 23068672LL);
    u16*   sc   = (u16*)(ws + 56623104LL);
    u16*   P    = (u16*)(ws + 90177536LL);
    u16*   vt   = (u16*)(ws + 123731968LL);
    float* part = (float*)(ws + 140509184LL);   // total 157,286,400 bytes

    // 1. casts (x + 3 weights, one dispatch)
    cast_all_kernel<<<11264, 256, 0, stream>>>(x, wq, wk, wv, xb);

    // 2. QK projection: 256^2 8-phase, exactly 256 blocks (1/CU, no tail)
    gemm_qk256<<<256, 512, 0, stream>>>(xb, wb, qk);

    // 3. scores (544 blocks) + V projection (512 blocks), one dispatch
    gemm_sv<<<1056, 256, 0, stream>>>(qk, sc, xb, wb, vt);

    // 4. single-pass causal softmax -> P bf16 (paired-row balanced)
    softmax_kernel<<<dim3(1024, 1, 4), 256, 0, stream>>>(sc, P);

    // 5. PV split-K + combine
    gemm_pv<<<dim3(192, 1, 4), 256, 0, stream>>>(P, vt, out, part);
    pv_combine<<<2048, 256, 0, stream>>>(out, part);
}

// Round 4
// 235.466 us; speedup vs baseline: 1.0890x; 1.0529x over previous
//
#include <hip/hip_runtime.h>
#include <hip/hip_bf16.h>

// Causal attention, B=4 S=2048 E=1024 D=1024, fp32 in/out.
// Round 12:
//  - scores moved to the 256x256 8-phase core: 36 tiles/batch = 144 blocks
//    (8 XCD x 18), single residency round. Diagonal tiles compute full 256^2
//    (upper garbage is masked by softmax which only reads j<=i).
//  - V projection (512 x 128^2 blocks) moved into the softmax dispatch
//    (V depends only on cast; softmax is BW-bound, V compute-bound).
//  - chain: cast -> qk256(256) -> sc256(144) -> V+softmax(4608) -> pv -> comb.

typedef unsigned short u16;
typedef __attribute__((ext_vector_type(4))) u16   u16x4;
typedef __attribute__((ext_vector_type(8))) u16   u16x8;
typedef __attribute__((ext_vector_type(8))) short short8;
typedef __attribute__((ext_vector_type(4))) float f32x4;
typedef __attribute__((ext_vector_type(4))) int   i32x4;

__device__ inline u16 f2b(float v) {
    __hip_bfloat16 b = __float2bfloat16(v);
    return *reinterpret_cast<u16*>(&b);
}
__device__ inline float b2f(u16 v) {
    unsigned int u = ((unsigned int)v) << 16;
    return *reinterpret_cast<float*>(&u);
}

template <typename T> __device__ inline void store_elem(T* p, float v);
template <> __device__ inline void store_elem<float>(float* p, float v) { *p = v; }
template <> __device__ inline void store_elem<u16>(u16* p, float v)     { *p = f2b(v); }

// async global->LDS 16B per lane; LDS dest must be wave-uniform base + lane*16
__device__ inline void gload_lds16(const u16* g, u16* l) {
    __builtin_amdgcn_global_load_lds(
        (const __attribute__((address_space(1))) void*)g,
        (__attribute__((address_space(3))) void*)l, 16, 0, 0);
}

// ---------------- merged fp32 -> bf16 cast: [x | wq | wk | wv] -------------
__global__ __launch_bounds__(256) void cast_all_kernel(
    const float* __restrict__ x,  const float* __restrict__ wq,
    const float* __restrict__ wk, const float* __restrict__ wv,
    u16* __restrict__ dst) {
    int q = blockIdx.x * 256 + threadIdx.x;     // quad index, 2883584 total
    const float* src;
    int sidx;
    if (q < 2097152) { src = x; sidx = q * 4; }
    else {
        int qq = q - 2097152;
        int w  = qq >> 18;                      // 262144 quads per weight
        sidx   = (qq & 262143) * 4;
        src    = (w == 0) ? wq : (w == 1) ? wk : wv;
    }
    float4 v = *(const float4*)(src + sidx);
    u16x4 o;
    o.x = f2b(v.x); o.y = f2b(v.y); o.z = f2b(v.z); o.w = f2b(v.w);
    *(u16x4*)(dst + q * 4) = o;
}

// ---------------- 256x256 8-phase GEMM core (K=1024, C = A * B^T) ----------
// lds: caller-provided 2*2*16384 u16 (128 KiB). Dense OutT=u16 store.
__device__ __forceinline__ void gemm256_core(
    u16* __restrict__ lds,
    const u16* __restrict__ Ab, int lda,
    const u16* __restrict__ Bb, int ldb,
    u16* __restrict__ Cb, int ldc,
    int m0, int n0)
{
    const int tid  = threadIdx.x;
    const int lane = tid & 63;
    const int wave = tid >> 6;
    const int quad = lane >> 4;
    const int r16  = lane & 15;
    const int wm   = wave >> 2;   // 0..1  (M direction, 128 rows each)
    const int wn   = wave & 3;    // 0..3  (N direction, 64 cols each)

    // --- staging precompute: linear LDS dest, inverse-swizzled global src ---
    int gA[2][2], gB[2][2], lA[2][2], lB[2][2];
    {
        const int cswz = ((lane & 3) * 8) ^ (((lane >> 5) & 1) << 4);
        const int rsub = lane >> 2;
#pragma unroll
        for (int u = 0; u < 2; ++u)
#pragma unroll
            for (int j = 0; j < 2; ++j) {
                int s   = j * 8 + wave;
                int sh  = s >> 1, cg = s & 1;
                int rgA = (sh & 3) + (sh >> 2) * 8 + u * 4;
                int rgB = sh + u * 8;
                int cl  = cg * 32 + cswz;
                gA[u][j] = (m0 + rgA * 16 + rsub) * lda + cl;
                gB[u][j] = (n0 + rgB * 16 + rsub) * ldb + cl;
                lA[u][j] = (rgA * 2 + cg) * 512 + lane * 8;
                lB[u][j] = (rgB * 2 + cg) * 512 + lane * 8;
            }
    }

#define STAGE_A(BUF, U, KK) do { \
        gload_lds16(Ab + gA[U][0] + (KK), lds + (BUF)*32768 + lA[U][0]); \
        gload_lds16(Ab + gA[U][1] + (KK), lds + (BUF)*32768 + lA[U][1]); } while (0)
#define STAGE_B(BUF, U, KK) do { \
        gload_lds16(Bb + gB[U][0] + (KK), lds + (BUF)*32768 + 16384 + lB[U][0]); \
        gload_lds16(Bb + gB[U][1] + (KK), lds + (BUF)*32768 + 16384 + lB[U][1]); } while (0)

    // --- fragment read bases (same swizzle on the read side) ---
    const int cswr = (quad * 8) ^ ((r16 >> 3) << 4);
    const int rdA0 = wm * 16 * 512 + r16 * 32 + cswr;
    const int rdB0 = wn * 8  * 512 + r16 * 32 + cswr;

    f32x4 acc[8][4] = {};

    // prologue: tile0 -> buf0, tile1 -> buf1; wait tile0 (8 newest outstanding)
    STAGE_B(0, 0, 0);  STAGE_B(0, 1, 0);  STAGE_A(0, 0, 0);  STAGE_A(0, 1, 0);
    STAGE_B(1, 0, 64); STAGE_B(1, 1, 64); STAGE_A(1, 0, 64); STAGE_A(1, 1, 64);
    asm volatile("s_waitcnt vmcnt(8)" ::: "memory");
    __builtin_amdgcn_s_barrier();

    for (int t = 0; t < 16; ++t) {
        const int  buf = t & 1;
        const int  kk2 = t * 64 + 128;    // K offset of tile t+2 (same buffer)
        const bool pf  = (t < 14);
        const u16* Al  = lds + buf * 32768;
        const u16* Bl  = lds + buf * 32768 + 16384;
        short8 bfr[4][2], a01[2][2], a23[2][2], a45[2][2], a67[2][2];

        // ---- phase 1: read all B + A[0:2) (12 b128); MFMA mf 0-1 ----
#pragma unroll
        for (int nf = 0; nf < 4; ++nf)
#pragma unroll
            for (int ks = 0; ks < 2; ++ks)
                bfr[nf][ks] = *(const short8*)&Bl[rdB0 + (nf * 2 + ks) * 512];
#pragma unroll
        for (int mf = 0; mf < 2; ++mf)
#pragma unroll
            for (int ks = 0; ks < 2; ++ks)
                a01[mf][ks] = *(const short8*)&Al[rdA0 + (mf * 2 + ks) * 512];
        __builtin_amdgcn_s_barrier();
        __builtin_amdgcn_s_setprio(1);
#pragma unroll
        for (int mf = 0; mf < 2; ++mf)
#pragma unroll
            for (int nf = 0; nf < 4; ++nf)
#pragma unroll
                for (int ks = 0; ks < 2; ++ks)
                    acc[mf][nf] = __builtin_amdgcn_mfma_f32_16x16x32_bf16(
                        a01[mf][ks], bfr[nf][ks], acc[mf][nf], 0, 0, 0);
        __builtin_amdgcn_s_setprio(0);
        __builtin_amdgcn_s_barrier();

        // ---- phase 2: read A[2:4); stage B-h0(t+2); MFMA mf 2-3 ----
#pragma unroll
        for (int mf = 0; mf < 2; ++mf)
#pragma unroll
            for (int ks = 0; ks < 2; ++ks)
                a23[mf][ks] = *(const short8*)&Al[rdA0 + ((mf + 2) * 2 + ks) * 512];
        if (pf) STAGE_B(buf, 0, kk2);
        __builtin_amdgcn_s_barrier();
        __builtin_amdgcn_s_setprio(1);
#pragma unroll
        for (int mf = 0; mf < 2; ++mf)
#pragma unroll
            for (int nf = 0; nf < 4; ++nf)
#pragma unroll
                for (int ks = 0; ks < 2; ++ks)
                    acc[mf + 2][nf] = __builtin_amdgcn_mfma_f32_16x16x32_bf16(
                        a23[mf][ks], bfr[nf][ks], acc[mf + 2][nf], 0, 0, 0);
        __builtin_amdgcn_s_setprio(0);
        __builtin_amdgcn_s_barrier();

        // ---- phase 3: read A[4:8) (8 b128); stage B-h1(t+2); MFMA mf 4-5 ----
#pragma unroll
        for (int mf = 0; mf < 2; ++mf)
#pragma unroll
            for (int ks = 0; ks < 2; ++ks) {
                a45[mf][ks] = *(const short8*)&Al[rdA0 + ((mf + 4) * 2 + ks) * 512];
                a67[mf][ks] = *(const short8*)&Al[rdA0 + ((mf + 6) * 2 + ks) * 512];
            }
        if (pf) STAGE_B(buf, 1, kk2);
        __builtin_amdgcn_s_barrier();
        __builtin_amdgcn_s_setprio(1);
#pragma unroll
        for (int mf = 0; mf < 2; ++mf)
#pragma unroll
            for (int nf = 0; nf < 4; ++nf)
#pragma unroll
                for (int ks = 0; ks < 2; ++ks)
                    acc[mf + 4][nf] = __builtin_amdgcn_mfma_f32_16x16x32_bf16(
                        a45[mf][ks], bfr[nf][ks], acc[mf + 4][nf], 0, 0, 0);
        __builtin_amdgcn_s_setprio(0);
        // a67 is consumed only in phase 4: retire its ds_reads before the
        // barrier that lets other waves overwrite the A region.
        asm volatile("s_waitcnt lgkmcnt(0)" ::: "memory");
        __builtin_amdgcn_s_barrier();

        // ---- phase 4: stage A both units (t+2); MFMA mf 6-7; checkpoint ----
        if (pf) { STAGE_A(buf, 0, kk2); STAGE_A(buf, 1, kk2); }
        __builtin_amdgcn_s_barrier();
        __builtin_amdgcn_s_setprio(1);
#pragma unroll
        for (int mf = 0; mf < 2; ++mf)
#pragma unroll
            for (int nf = 0; nf < 4; ++nf)
#pragma unroll
                for (int ks = 0; ks < 2; ++ks)
                    acc[mf + 6][nf] = __builtin_amdgcn_mfma_f32_16x16x32_bf16(
                        a67[mf][ks], bfr[nf][ks], acc[mf + 6][nf], 0, 0, 0);
        __builtin_amdgcn_s_setprio(0);
        // counted checkpoint: leave exactly this iter's 8 stage-loads (tile
        // t+2) in flight; guarantees tile t+1 fully landed before next group.
        if (pf) asm volatile("s_waitcnt vmcnt(8)" ::: "memory");
        else    asm volatile("s_waitcnt vmcnt(0)" ::: "memory");
        __builtin_amdgcn_s_barrier();
    }
#undef STAGE_A
#undef STAGE_B

    // ---- epilogue: C/D layout col=lane&15, row=quad*4+reg ----
#pragma unroll
    for (int mf = 0; mf < 8; ++mf) {
        int m = m0 + wm * 128 + mf * 16 + quad * 4;
#pragma unroll
        for (int nf = 0; nf < 4; ++nf) {
            int n = n0 + wn * 64 + nf * 16 + r16;
#pragma unroll
            for (int r = 0; r < 4; ++r)
                Cb[(m + r) * ldc + n] = f2b(acc[mf][nf][r]);
        }
    }
}

// qk = xb[8192,1024] x wb[0:2048]^T; 256 blocks = 1/CU exactly.
__global__ __launch_bounds__(512) void gemm_qk256(
    const u16* __restrict__ xb, const u16* __restrict__ wb,
    u16* __restrict__ qk)
{
    __shared__ __align__(16) u16 lds[2 * 2 * 16384];
    int flat = blockIdx.x;                     // 0..255
    int swz  = (flat & 7) * 32 + (flat >> 3);  // bijective XCD swizzle
    int m0   = (swz >> 3) * 256;
    int n0   = (swz & 7) * 256;
    gemm256_core(lds, xb, 1024, wb, 1024, qk, 2048, m0, n0);
}

// scores: per batch 36 lower-tri 256^2 tiles (diag tiles full; upper garbage
// masked by softmax). 144 blocks = 8 XCD x 18.
__global__ __launch_bounds__(512) void gemm_sc256(
    const u16* __restrict__ qk, u16* __restrict__ sc)
{
    __shared__ __align__(16) u16 lds[2 * 2 * 16384];
    int flat = blockIdx.x;                     // 0..143
    int swz  = (flat & 7) * 18 + (flat >> 3);  // each XCD: 18 consecutive
    int z    = swz / 36;
    int t    = swz - z * 36;                   // 0..35 lower-tri (8x8)
    float ff = sqrtf(8.0f * t + 1.0f);
    int m = (int)((ff - 1.0f) * 0.5f);
    while ((m + 1) * (m + 2) / 2 <= t) m++;
    while (m * (m + 1) / 2 > t) m--;
    int n = t - m * (m + 1) / 2;
    const u16* Ab = qk + (long long)z * 2048 * 2048;
    gemm256_core(lds, Ab, 2048, Ab + 1024, 2048,
                 sc + (long long)z * 2048 * 2048, 2048, m * 256, n * 256);
}

// ---------------- BT-GEMM core 128^2 (V / pv) -------------------------------
#define MT 128
#define NT 128
#define BKH 32
#define HSZ (MT * BKH)   // elems per half buffer = 4096

template <int TRANS, typename OutT>
__device__ __forceinline__ void gemm_core(
    u16* __restrict__ As, u16* __restrict__ Bs,
    const u16* __restrict__ Ab, int lda,
    const u16* __restrict__ Bb, int ldb,
    OutT* __restrict__ Cb, int ldc,
    int m0, int n0, int kbeg, int kend)
{
    const int tid  = threadIdx.x;
    const int lane = tid & 63;
    const int wave = tid >> 6;
    const int quad = lane >> 4;
    const int r16  = lane & 15;
    const int mw   = (wave >> 1) * 64;
    const int nw   = (wave & 1) * 64;

    const int c0 = tid, c1 = tid + 256;
    const int r0 = c0 >> 2, k0 = (c0 & 3) * 8;
    const int r1 = c1 >> 2, k1 = (c1 & 3) * 8;
    const int oa0 = (m0 + r0) * lda + k0;
    const int oa1 = (m0 + r1) * lda + k1;
    const int ob0 = (n0 + r0) * ldb + k0;
    const int ob1 = (n0 + r1) * ldb + k1;

    f32x4 acc[4][4] = {};

    for (int kk = kbeg; kk < kend; kk += 2 * BKH) {
        __syncthreads();
        gload_lds16(Ab + (kk + oa0),        &As[c0 * 8]);
        gload_lds16(Ab + (kk + oa1),        &As[c1 * 8]);
        gload_lds16(Ab + (kk + BKH + oa0),  &As[HSZ + c0 * 8]);
        gload_lds16(Ab + (kk + BKH + oa1),  &As[HSZ + c1 * 8]);
        gload_lds16(Bb + (kk + ob0),        &Bs[c0 * 8]);
        gload_lds16(Bb + (kk + ob1),        &Bs[c1 * 8]);
        gload_lds16(Bb + (kk + BKH + ob0),  &Bs[HSZ + c0 * 8]);
        gload_lds16(Bb + (kk + BKH + ob1),  &Bs[HSZ + c1 * 8]);
        __syncthreads();

#pragma unroll
        for (int h = 0; h < 2; h++) {
            short8 af[4], bf[4];
#pragma unroll
            for (int i = 0; i < 4; i++)
                af[i] = *(const short8*)&As[h * HSZ + (mw + i * 16 + r16) * BKH + quad * 8];
#pragma unroll
            for (int j = 0; j < 4; j++)
                bf[j] = *(const short8*)&Bs[h * HSZ + (nw + j * 16 + r16) * BKH + quad * 8];
#pragma unroll
            for (int i = 0; i < 4; i++)
#pragma unroll
                for (int j = 0; j < 4; j++)
                    acc[i][j] = __builtin_amdgcn_mfma_f32_16x16x32_bf16(af[i], bf[j], acc[i][j], 0, 0, 0);
        }
    }

    // epilogue: C/D layout col=lane&15, row=quad*4+reg
    if (TRANS == 0) {
#pragma unroll
        for (int i = 0; i < 4; i++)
#pragma unroll
            for (int j = 0; j < 4; j++)
#pragma unroll
                for (int r = 0; r < 4; r++) {
                    int m = m0 + mw + i * 16 + quad * 4 + r;
                    int n = n0 + nw + j * 16 + r16;
                    store_elem(&Cb[(long long)m * ldc + n], acc[i][j][r]);
                }
    } else {
#pragma unroll
        for (int i = 0; i < 4; i++)
#pragma unroll
            for (int j = 0; j < 4; j++) {
                int mbase = m0 + mw + i * 16 + quad * 4;      // 4-aligned
                int d     = n0 + nw + j * 16 + r16;
                int b     = mbase >> 11;
                int s     = mbase & 2047;
                u16x4 o;
#pragma unroll
                for (int r = 0; r < 4; r++) o[r] = f2b(acc[i][j][r]);
                *(u16x4*)((u16*)Cb + (((b << 10) + d) * 2048 + s)) = o;
            }
    }
}

// ---------------- single-pass causal softmax row pair ----------------------
__device__ __forceinline__ void softmax_row(const u16* __restrict__ sc,
                                            u16* __restrict__ P, int row,
                                            float* __restrict__ red) {
    const int S = 2048;
    int i   = row & (S - 1);
    int n   = i + 1;
    int kendr = (i & ~127) + 128;
    const u16* srow = sc + (long long)row * S;
    u16*       prow = P  + (long long)row * S;

    int j0 = threadIdx.x * 8;
    u16x8 raw = {};
    if (j0 <= i) raw = *(const u16x8*)(srow + j0);
    float v[8];
#pragma unroll
    for (int e = 0; e < 8; e++) v[e] = (j0 + e < n) ? b2f(raw[e]) : -1e30f;

    float lmax = v[0];
#pragma unroll
    for (int e = 1; e < 8; e++) lmax = fmaxf(lmax, v[e]);
    for (int o = 32; o > 0; o >>= 1) lmax = fmaxf(lmax, __shfl_xor(lmax, o, 64));
    int wid = threadIdx.x >> 6;
    if ((threadIdx.x & 63) == 0) red[wid] = lmax;
    __syncthreads();
    float Mx = fmaxf(fmaxf(red[0], red[1]), fmaxf(red[2], red[3]));

    // exp((s-Mx)/32) = exp2((s-Mx) * (1/(32 ln2)))
    const float C = 0.045112384f;
    float ev[8];
    float lsum = 0.f;
#pragma unroll
    for (int e = 0; e < 8; e++) {
        ev[e] = (j0 + e < n) ? exp2f((v[e] - Mx) * C) : 0.f;
        lsum += ev[e];
    }
    for (int o = 32; o > 0; o >>= 1) lsum += __shfl_xor(lsum, o, 64);
    if ((threadIdx.x & 63) == 0) red[4 + wid] = lsum;
    __syncthreads();
    float inv = 1.0f / (red[4] + red[5] + red[6] + red[7]);

    if (j0 < kendr) {
        u16x8 o8;
#pragma unroll
        for (int e = 0; e < 8; e++) o8[e] = f2b(ev[e] * inv);
        *(u16x8*)(prow + j0) = o8;
    }
}

// V projection (512 blocks, first so they're resident early) + paired-row
// softmax (4096 blocks). V depends only on cast; softmax only on sc.
__global__ __launch_bounds__(256, 4) void v_softmax(
    const u16* __restrict__ xb, const u16* __restrict__ wb,
    u16* __restrict__ vt,
    const u16* __restrict__ sc, u16* __restrict__ P)
{
    __shared__ __align__(16) u16 As[2 * HSZ];
    __shared__ __align__(16) u16 Bs[2 * HSZ];
    int bid = blockIdx.x;
    if (bid < 512) {
        int vb = (bid & 7) * 64 + (bid >> 3);   // XCD-chunked
        int m0 = (vb >> 3) * MT;
        int n0 = (vb & 7) * NT;
        gemm_core<1, u16>(As, Bs, xb, 1024, wb + 2048 * 1024, 1024, vt, 2048,
                          m0, n0, 0, 1024);
    } else {
        float* red = (float*)As;
        int sid = bid - 512;                    // 0..4095
        int z = sid >> 10, i = sid & 1023;
        softmax_row(sc, P, z * 2048 + (2047 - i), red);
        softmax_row(sc, P, z * 2048 + i, red);
    }
}

// PV split-K, longest-first schedule: per batch 192 units.
__global__ __launch_bounds__(256, 4) void gemm_pv(
    const u16* __restrict__ P, const u16* __restrict__ vt,
    float* __restrict__ out, float* __restrict__ part)
{
    __shared__ __align__(16) u16 As[2 * HSZ];
    __shared__ __align__(16) u16 Bs[2 * HSZ];
    const int bid = blockIdx.x;
    int m, chunk, n;
    if (bid < 80) {                       // K = 1024 class
        int q = bid >> 3; n = bid & 7;
        if (q < 9) { m = 7 + q; chunk = 0; } else { m = 15; chunk = 1; }
    } else {                              // K = s*128, s = 7..1
        int r = bid - 80; int s = 7 - (r >> 4); int t = r & 15;
        n = t & 7;
        if (t < 8) { m = s - 1; chunk = 0; } else { m = s + 7; chunk = 1; }
    }
    const int m0 = m * MT, n0 = n * NT;
    const int kbeg = chunk ? 1024 : 0;
    const int kend = chunk ? (m0 + MT) : min(1024, m0 + MT);
    const int b = blockIdx.z;

    const u16* Ab = P  + (long long)b * 2048 * 2048;
    const u16* Bb = vt + (long long)b * 1024 * 2048;
    float* Cb = (chunk == 0)
        ? out  + (long long)b * 2097152
        : part + (long long)b * 1048576 - 1024LL * 1024;   // rows (m-1024)
    gemm_core<0, float>(As, Bs, Ab, 2048, Bb, 2048, Cb, 1024, m0, n0, kbeg, kend);
}

// combine: out[b][1024+r][c] += part[b][r][c]
__global__ __launch_bounds__(256) void pv_combine(float* __restrict__ out,
                                                  const float* __restrict__ part) {
    long long idx = ((long long)blockIdx.x * 256 + threadIdx.x) * 8;
    long long bb = idx >> 20;
    long long j  = idx & 1048575;
    float* o = out + bb * 2097152 + 1048576 + j;
    const float* p = part + bb * 1048576 + j;
    float4 o0 = *(float4*)o, o1 = *(float4*)(o + 4);
    float4 p0 = *(const float4*)p, p1 = *(const float4*)(p + 4);
    o0.x += p0.x; o0.y += p0.y; o0.z += p0.z; o0.w += p0.w;
    o1.x += p1.x; o1.y += p1.y; o1.z += p1.z; o1.w += p1.w;
    *(float4*)o = o0; *(float4*)(o + 4) = o1;
}

extern "C" void kernel_launch(void* const* d_in, const int* in_sizes, int n_in,
                              void* d_out, int out_size, void* d_ws, size_t ws_size,
                              hipStream_t stream) {
    const float* x  = (const float*)d_in[0];
    const float* wq = (const float*)d_in[1];
    const float* wk = (const float*)d_in[2];
    const float* wv = (const float*)d_in[3];
    float* out = (float*)d_out;

    char* ws = (char*)d_ws;
    // layout: xb 16M | wb 6M | qk 32M | sc 32M | P 32M | vt 16M | part 16M
    u16*   xb   = (u16*)(ws);
    u16*   wb   = (u16*)(ws + 16777216LL);
    u16*   qk   = (u16*)(ws + 23068672LL);
    u16*   sc   = (u16*)(ws + 56623104LL);
    u16*   P    = (u16*)(ws + 90177536LL);
    u16*   vt   = (u16*)(ws + 123731968LL);
    float* part = (float*)(ws + 140509184LL);   // total 157,286,400 bytes

    // 1. casts (x + 3 weights, one dispatch)
    cast_all_kernel<<<11264, 256, 0, stream>>>(x, wq, wk, wv, xb);

    // 2. QK projection: 256^2 8-phase, exactly 256 blocks (1/CU, no tail)
    gemm_qk256<<<256, 512, 0, stream>>>(xb, wb, qk);

    // 3. scores: 256^2 8-phase, 144 blocks (single round)
    gemm_sc256<<<144, 512, 0, stream>>>(qk, sc);

    // 4. V projection + causal softmax, one dispatch
    v_softmax<<<4608, 256, 0, stream>>>(xb, wb, vt, sc, P);

    // 5. PV split-K + combine
    gemm_pv<<<dim3(192, 1, 4), 256, 0, stream>>>(P, vt, out, part);
    pv_combine<<<2048, 256, 0, stream>>>(out, part);
}